// Round 6
// baseline (408.567 us; speedup 1.0000x reference)
//
#include <hip/hip_runtime.h>
#include <math.h>

// Problem constants
#define NREL 499        // 2*MAX_LEN-1
#define NREL_PAD 500    // row stride for qrel (ushort fp16)
#define LDB 72          // bf16 LDS row stride (P buffer)

typedef __attribute__((ext_vector_type(8))) short bf16x8;
typedef __attribute__((ext_vector_type(4))) float f32x4;

__device__ __forceinline__ float bf2f(ushort x) {
  union { unsigned u; float f; } v; v.u = ((unsigned)x) << 16; return v.f;
}
__device__ __forceinline__ ushort f2bf(float x) {
  union { float f; unsigned u; } v; v.f = x;
  return (ushort)((v.u + 0x8000u) >> 16);
}
__device__ __forceinline__ ushort f2h(float x) {
  union { _Float16 h; ushort u; } v; v.h = (_Float16)x; return v.u;
}
__device__ __forceinline__ float h2f(ushort u) {
  union { _Float16 h; ushort u; } v; v.u = u; return (float)v.h;
}
__device__ __forceinline__ bf16x8 pack8(float4 a, float4 b) {
  bf16x8 r;
  r[0] = (short)f2bf(a.x); r[1] = (short)f2bf(a.y);
  r[2] = (short)f2bf(a.z); r[3] = (short)f2bf(a.w);
  r[4] = (short)f2bf(b.x); r[5] = (short)f2bf(b.y);
  r[6] = (short)f2bf(b.z); r[7] = (short)f2bf(b.w);
  return r;
}
// residual (lo) pack: lo = bf16(x - float(hi))
__device__ __forceinline__ bf16x8 packlo8(float4 a, float4 b, bf16x8 hi) {
  bf16x8 r;
  r[0] = (short)f2bf(a.x - bf2f((ushort)hi[0]));
  r[1] = (short)f2bf(a.y - bf2f((ushort)hi[1]));
  r[2] = (short)f2bf(a.z - bf2f((ushort)hi[2]));
  r[3] = (short)f2bf(a.w - bf2f((ushort)hi[3]));
  r[4] = (short)f2bf(b.x - bf2f((ushort)hi[4]));
  r[5] = (short)f2bf(b.y - bf2f((ushort)hi[5]));
  r[6] = (short)f2bf(b.z - bf2f((ushort)hi[6]));
  r[7] = (short)f2bf(b.w - bf2f((ushort)hi[7]));
  return r;
}

// ============================================================================
// prep_wt: Whi/Wlo[z][n][k] (bf16) = split of W_z[k][n]. Grid (8,8,4).
// ============================================================================
__global__ __launch_bounds__(256) void prep_wt(const float* __restrict__ W0,
                                               const float* __restrict__ W1,
                                               const float* __restrict__ W2,
                                               const float* __restrict__ W3,
                                               ushort* __restrict__ Whi,
                                               ushort* __restrict__ Wlo) {
  __shared__ float T[64][68];
  const int t = threadIdx.x;
  const int k0 = blockIdx.x * 64, n0 = blockIdx.y * 64, z = blockIdx.z;
  const float* W = (z == 0) ? W0 : (z == 1) ? W1 : (z == 2) ? W2 : W3;
#pragma unroll
  for (int s = 0; s < 4; ++s) {
    int idx = t + s * 256;
    int r = idx >> 4, c4 = (idx & 15) << 2;
    *(float4*)&T[r][c4] = *(const float4*)(W + (size_t)(k0 + r) * 512 + n0 + c4);
  }
  __syncthreads();
#pragma unroll
  for (int s = 0; s < 4; ++s) {
    int idx = t + s * 256;
    int row = idx >> 4, c4 = (idx & 15) << 2;  // row = n_local, c4 = k_local
    float x[4] = {T[c4 + 0][row], T[c4 + 1][row], T[c4 + 2][row], T[c4 + 3][row]};
    ushort h[4], l[4];
#pragma unroll
    for (int e = 0; e < 4; ++e) {
      h[e] = f2bf(x[e]);
      l[e] = f2bf(x[e] - bf2f(h[e]));
    }
    size_t off = (size_t)z * 262144 + (size_t)(n0 + row) * 512 + k0 + c4;
    *(ushort4*)(Whi + off) = make_ushort4(h[0], h[1], h[2], h[3]);
    *(ushort4*)(Wlo + off) = make_ushort4(l[0], l[1], l[2], l[3]);
  }
}

// ============================================================================
// proj_qkv: fused Q/K/V projection (z = blockIdx.z selects input/output).
// z<2: out [bh][l][64] (Q,K row-major head-split); z==2: Vt [bh][d][l].
// Tile 64x64, no LDS; W hi/lo split (2 MFMA) -> GEMM error ~ A-pack only.
// ============================================================================
__global__ __launch_bounds__(256) void proj_qkv(
    const float* __restrict__ Aq, const float* __restrict__ Ak,
    const float* __restrict__ Av, const ushort* __restrict__ Whi,
    const ushort* __restrict__ Wlo, const float* __restrict__ bq,
    const float* __restrict__ bk, const float* __restrict__ bv,
    ushort* __restrict__ Qw, ushort* __restrict__ Kw, ushort* __restrict__ Vt) {
  const int t = threadIdx.x;
  const int lane = t & 63, wave = t >> 6;
  const int m16 = lane & 15, quad = lane >> 4;
  const int i0 = blockIdx.y * 64;
  const int n0 = blockIdx.x * 64;
  const int z = blockIdx.z;
  const float* A = (z == 0) ? Aq : (z == 1) ? Ak : Av;
  const float* bias = (z == 0) ? bq : (z == 1) ? bk : bv;
  const ushort* Wh = Whi + (size_t)z * 262144;
  const ushort* Wl = Wlo + (size_t)z * 262144;
  f32x4 acc[4] = {{0.f, 0.f, 0.f, 0.f}, {0.f, 0.f, 0.f, 0.f},
                  {0.f, 0.f, 0.f, 0.f}, {0.f, 0.f, 0.f, 0.f}};

  if (z < 2) {
    const float* arow = A + (size_t)(i0 + (wave << 4) + m16) * 512 + (quad << 3);
#pragma unroll 4
    for (int kc = 0; kc < 16; ++kc) {
      bf16x8 af = pack8(*(const float4*)(arow + kc * 32),
                        *(const float4*)(arow + kc * 32 + 4));
#pragma unroll
      for (int nt = 0; nt < 4; ++nt) {
        size_t woff = (size_t)(n0 + (nt << 4) + m16) * 512 + kc * 32 + (quad << 3);
        bf16x8 wh = *(const bf16x8*)(Wh + woff);
        bf16x8 wl = *(const bf16x8*)(Wl + woff);
        acc[nt] = __builtin_amdgcn_mfma_f32_16x16x32_bf16(af, wh, acc[nt], 0, 0, 0);
        acc[nt] = __builtin_amdgcn_mfma_f32_16x16x32_bf16(af, wl, acc[nt], 0, 0, 0);
      }
    }
    ushort* out = (z == 0) ? Qw : Kw;
    const int b = i0 >> 11, l0 = i0 & 2047, h = n0 >> 6;
#pragma unroll
    for (int nt = 0; nt < 4; ++nt) {
      float bn = bias[n0 + (nt << 4) + m16];
      int d = (nt << 4) + m16;
#pragma unroll
      for (int r = 0; r < 4; ++r) {
        int il = (wave << 4) + (quad << 2) + r;
        out[((size_t)(b * 8 + h) * 2048 + l0 + il) * 64 + d] = f2bf(acc[nt][r] + bn);
      }
    }
  } else {
    // rows = n (d), cols = i -> coalesced Vt stores
    const size_t wbase = (size_t)(n0 + (wave << 4) + m16) * 512 + (quad << 3);
#pragma unroll 2
    for (int kc = 0; kc < 16; ++kc) {
      bf16x8 wh = *(const bf16x8*)(Wh + wbase + kc * 32);
      bf16x8 wl = *(const bf16x8*)(Wl + wbase + kc * 32);
#pragma unroll
      for (int it = 0; it < 4; ++it) {
        const float* ap = A + (size_t)(i0 + (it << 4) + m16) * 512 + kc * 32 + (quad << 3);
        bf16x8 af = pack8(*(const float4*)ap, *(const float4*)(ap + 4));
        acc[it] = __builtin_amdgcn_mfma_f32_16x16x32_bf16(wh, af, acc[it], 0, 0, 0);
        acc[it] = __builtin_amdgcn_mfma_f32_16x16x32_bf16(wl, af, acc[it], 0, 0, 0);
      }
    }
    const int b = i0 >> 11, l0 = i0 & 2047, h = n0 >> 6;
    float4 b4 = *(const float4*)(bias + n0 + (wave << 4) + (quad << 2));
    float bb[4] = {b4.x, b4.y, b4.z, b4.w};
#pragma unroll
    for (int r = 0; r < 4; ++r) {
      int d = (wave << 4) + (quad << 2) + r;
#pragma unroll
      for (int it = 0; it < 4; ++it) {
        Vt[((size_t)(b * 8 + h) * 64 + d) * 2048 + l0 + (it << 4) + m16] =
            f2bf(acc[it][r] + bb[r]);
      }
    }
  }
}

// ============================================================================
// qrel_mfma: qrelh[bh][i][r] (fp16, stride NREL_PAD) = sum_d Q[i,d]*rel[r,d].
// rel hi/lo split (Q already exact bf16) -> ~fp32 compute; fp16 store
// (abs err ~4e-3 at |qrel|<=8 vs bf16's 3e-2). Grid (8, 32, 16).
// ============================================================================
__global__ __launch_bounds__(256) void qrel_mfma(const ushort* __restrict__ Qw,
                                                 const float* __restrict__ rel,
                                                 ushort* __restrict__ qrelh) {
  const int t = threadIdx.x;
  const int lane = t & 63, wave = t >> 6;
  const int m16 = lane & 15, quad = lane >> 4;
  const int r0 = blockIdx.x * 64;
  const int i0 = blockIdx.y * 64;
  const int bh = blockIdx.z;
  const ushort* Qb = Qw + ((size_t)bh * 2048 + i0 + (wave << 4) + m16) * 64;
  bf16x8 qa0 = *(const bf16x8*)(Qb + (quad << 3));
  bf16x8 qa1 = *(const bf16x8*)(Qb + 32 + (quad << 3));

  f32x4 acc[4] = {{0.f, 0.f, 0.f, 0.f}, {0.f, 0.f, 0.f, 0.f},
                  {0.f, 0.f, 0.f, 0.f}, {0.f, 0.f, 0.f, 0.f}};
#pragma unroll
  for (int rt = 0; rt < 4; ++rt) {
    int rr = min(r0 + (rt << 4) + m16, NREL - 1);
    const float* rp = rel + (size_t)rr * 64 + (quad << 3);
    float4 a0 = *(const float4*)rp, a1 = *(const float4*)(rp + 4);
    float4 b0 = *(const float4*)(rp + 32), b1 = *(const float4*)(rp + 36);
    bf16x8 h0 = pack8(a0, a1), h1 = pack8(b0, b1);
    bf16x8 l0 = packlo8(a0, a1, h0), l1 = packlo8(b0, b1, h1);
    acc[rt] = __builtin_amdgcn_mfma_f32_16x16x32_bf16(qa0, h0, acc[rt], 0, 0, 0);
    acc[rt] = __builtin_amdgcn_mfma_f32_16x16x32_bf16(qa1, h1, acc[rt], 0, 0, 0);
    acc[rt] = __builtin_amdgcn_mfma_f32_16x16x32_bf16(qa0, l0, acc[rt], 0, 0, 0);
    acc[rt] = __builtin_amdgcn_mfma_f32_16x16x32_bf16(qa1, l1, acc[rt], 0, 0, 0);
  }
#pragma unroll
  for (int rt = 0; rt < 4; ++rt) {
    int r = r0 + (rt << 4) + m16;
    if (r < NREL_PAD) {
#pragma unroll
      for (int rg = 0; rg < 4; ++rg) {
        int i = i0 + (wave << 4) + (quad << 2) + rg;
        qrelh[((size_t)bh * 2048 + i) * NREL_PAD + r] = f2h(acc[rt][rg]);
      }
    }
  }
}

// ============================================================================
// flash_attn, split-j x4, barrier-free: grid (32 i-tiles, 16 bh, 4 jc).
// All Q/K/V fragments direct from global (L2-resident); LDS only for the
// wave-private P layout round-trip. Writes unnormalized partial O (bf16)
// + per-row m,l for the merge pass.
// ============================================================================
__global__ __launch_bounds__(256) void flash_attn(
    const ushort* __restrict__ Qw, const ushort* __restrict__ Kw,
    const ushort* __restrict__ Vt, const ushort* __restrict__ qrelh,
    const int* __restrict__ mask, ushort* __restrict__ Opart,
    float* __restrict__ mbuf, float* __restrict__ lbuf) {
  __shared__ ushort Ps[64 * LDB];  // P [i][j], wave-private 16-row strips
  const int t = threadIdx.x;
  const int lane = t & 63, wave = t >> 6;
  const int m16 = lane & 15, quad = lane >> 4;
  const int koff = quad << 3;
  const int i0 = blockIdx.x * 64;
  const int bh = blockIdx.y;
  const int jc = blockIdx.z;
  const int b = bh >> 3;
  const ushort* Qb = Qw + (size_t)bh * 2048 * 64;
  const ushort* Kb = Kw + (size_t)bh * 2048 * 64;
  const ushort* Vb = Vt + (size_t)bh * 64 * 2048;
  const ushort* qrl = qrelh + (size_t)bh * 2048 * NREL_PAD;
  const int* mb = mask + b * 2048;

  // Q A-fragments straight from global (16-B contiguous per lane)
  const ushort* qrow = Qb + (size_t)(i0 + (wave << 4) + m16) * 64;
  bf16x8 qa0 = *(const bf16x8*)(qrow + koff);
  bf16x8 qa1 = *(const bf16x8*)(qrow + 32 + koff);

  float m_i[4], l_i[4];
  f32x4 oacc[4];
#pragma unroll
  for (int r = 0; r < 4; ++r) { m_i[r] = -INFINITY; l_i[r] = 0.f; }
#pragma unroll
  for (int dt = 0; dt < 4; ++dt) oacc[dt] = (f32x4){0.f, 0.f, 0.f, 0.f};

  const int irow0 = i0 + (wave << 4) + (quad << 2);
  const int jbase = jc * 512;

  for (int j0 = jbase; j0 < jbase + 512; j0 += 64) {
    // S = Q Kt  (K B-frags direct from global)
    f32x4 sacc[4];
#pragma unroll
    for (int jt = 0; jt < 4; ++jt) {
      const ushort* krow = Kb + (size_t)(j0 + (jt << 4) + m16) * 64;
      bf16x8 kb0 = *(const bf16x8*)(krow + koff);
      bf16x8 kb1 = *(const bf16x8*)(krow + 32 + koff);
      f32x4 z = {0.f, 0.f, 0.f, 0.f};
      z = __builtin_amdgcn_mfma_f32_16x16x32_bf16(qa0, kb0, z, 0, 0, 0);
      z = __builtin_amdgcn_mfma_f32_16x16x32_bf16(qa1, kb1, z, 0, 0, 0);
      sacc[jt] = z;
    }

    // bias gather + mask (C-layout: row = quad*4+r, col = jt*16+m16)
    float sv[4][4];
    int mk[4];
#pragma unroll
    for (int jt = 0; jt < 4; ++jt) mk[jt] = mb[j0 + (jt << 4) + m16];
#pragma unroll
    for (int jt = 0; jt < 4; ++jt) {
      int j = j0 + (jt << 4) + m16;
#pragma unroll
      for (int r = 0; r < 4; ++r) {
        int i = irow0 + r;
        int rr = min(NREL - 1, max(0, j - i + (NREL / 2)));
        float sc = sacc[jt][r] * 0.125f + h2f(qrl[(size_t)i * NREL_PAD + rr]);
        sv[jt][r] = (mk[jt] == 0) ? -1e10f : sc;
      }
    }

    // online softmax per row
    float al[4];
#pragma unroll
    for (int r = 0; r < 4; ++r) {
      float mx = fmaxf(fmaxf(sv[0][r], sv[1][r]), fmaxf(sv[2][r], sv[3][r]));
#pragma unroll
      for (int w = 1; w < 16; w <<= 1) mx = fmaxf(mx, __shfl_xor(mx, w, 16));
      float mnew = fmaxf(m_i[r], mx);
      al[r] = __expf(m_i[r] - mnew);
      float sum = 0.f;
#pragma unroll
      for (int jt = 0; jt < 4; ++jt) {
        float p = __expf(sv[jt][r] - mnew);
        sv[jt][r] = p;
        sum += p;
      }
#pragma unroll
      for (int w = 1; w < 16; w <<= 1) sum += __shfl_xor(sum, w, 16);
      m_i[r] = mnew;
      l_i[r] = l_i[r] * al[r] + sum;
#pragma unroll
      for (int dt = 0; dt < 4; ++dt) oacc[dt][r] *= al[r];
    }

    // P -> LDS (wave-private strip), drain own DS ops, read back as A-frags
    const int prow0 = (wave << 4) + (quad << 2);
#pragma unroll
    for (int jt = 0; jt < 4; ++jt)
#pragma unroll
      for (int r = 0; r < 4; ++r)
        Ps[(prow0 + r) * LDB + (jt << 4) + m16] = f2bf(sv[jt][r]);
    __asm__ volatile("s_waitcnt lgkmcnt(0)" ::: "memory");

    bf16x8 pa0 = *(const bf16x8*)&Ps[((wave << 4) + m16) * LDB + koff];
    bf16x8 pa1 = *(const bf16x8*)&Ps[((wave << 4) + m16) * LDB + 32 + koff];

    // O += P V  (V B-frags direct from global; Vt is [d][l])
#pragma unroll
    for (int dt = 0; dt < 4; ++dt) {
      const ushort* vrow = Vb + (size_t)((dt << 4) + m16) * 2048 + j0;
      bf16x8 vb0 = *(const bf16x8*)(vrow + koff);
      bf16x8 vb1 = *(const bf16x8*)(vrow + 32 + koff);
      oacc[dt] = __builtin_amdgcn_mfma_f32_16x16x32_bf16(pa0, vb0, oacc[dt], 0, 0, 0);
      oacc[dt] = __builtin_amdgcn_mfma_f32_16x16x32_bf16(pa1, vb1, oacc[dt], 0, 0, 0);
    }
  }

  // epilogue: unnormalized partial O (bf16) + m,l
  const size_t obase = (size_t)(jc * 16 + bh) * 2048;
#pragma unroll
  for (int r = 0; r < 4; ++r) {
    int i = irow0 + r;
#pragma unroll
    for (int dt = 0; dt < 4; ++dt)
      Opart[(obase + i) * 64 + (dt << 4) + m16] = f2bf(oacc[dt][r]);
  }
  if (m16 == 0) {
#pragma unroll
    for (int r = 0; r < 4; ++r) {
      mbuf[obase + irow0 + r] = m_i[r];
      lbuf[obase + irow0 + r] = l_i[r];
    }
  }
}

// ============================================================================
// merge_attn: combine 4 j-chunks -> attn (bf16 [b][l][512]). Grid 128x256.
// ============================================================================
__global__ __launch_bounds__(256) void merge_attn(const ushort* __restrict__ Opart,
                                                  const float* __restrict__ mbuf,
                                                  const float* __restrict__ lbuf,
                                                  ushort* __restrict__ attn) {
  int g = blockIdx.x * 256 + threadIdx.x;  // 0..32767
  int bh = g >> 11, i = g & 2047;
  int b = bh >> 3, h = bh & 7;
  float mc[4], lc[4];
#pragma unroll
  for (int c = 0; c < 4; ++c) {
    mc[c] = mbuf[(size_t)(c * 16 + bh) * 2048 + i];
    lc[c] = lbuf[(size_t)(c * 16 + bh) * 2048 + i];
  }
  float ms = fmaxf(fmaxf(mc[0], mc[1]), fmaxf(mc[2], mc[3]));
  float wc[4], ls = 0.f;
#pragma unroll
  for (int c = 0; c < 4; ++c) { wc[c] = __expf(mc[c] - ms); ls += wc[c] * lc[c]; }
  float inv = 1.0f / ls;
  ushort* dst = attn + ((size_t)b * 2048 + i) * 512 + h * 64;
#pragma unroll
  for (int dc = 0; dc < 8; ++dc) {
    float acc[8] = {};
#pragma unroll
    for (int c = 0; c < 4; ++c) {
      uint4 raw = *(const uint4*)(Opart + ((size_t)(c * 16 + bh) * 2048 + i) * 64 + dc * 8);
      const ushort* rp = (const ushort*)&raw;
#pragma unroll
      for (int e = 0; e < 8; ++e) acc[e] += wc[c] * bf2f(rp[e]);
    }
    ushort o8[8];
#pragma unroll
    for (int e = 0; e < 8; ++e) o8[e] = f2bf(acc[e] * inv);
    *(uint4*)(dst + dc * 8) = *(const uint4*)o8;
  }
}

// ============================================================================
// out_proj: out[4096][512] fp32 = attn(bf16) @ (Whi+Wlo)^T + bo. Tile 64x64.
// ============================================================================
__global__ __launch_bounds__(256) void out_proj(const ushort* __restrict__ attn,
                                                const ushort* __restrict__ Whi,
                                                const ushort* __restrict__ Wlo,
                                                const float* __restrict__ bias,
                                                float* __restrict__ out) {
  const int t = threadIdx.x;
  const int lane = t & 63, wave = t >> 6;
  const int m16 = lane & 15, quad = lane >> 4;
  const int i0 = blockIdx.y * 64;
  const int n0 = blockIdx.x * 64;
  const ushort* arow = attn + (size_t)(i0 + (wave << 4) + m16) * 512 + (quad << 3);
  f32x4 acc[4] = {{0.f, 0.f, 0.f, 0.f}, {0.f, 0.f, 0.f, 0.f},
                  {0.f, 0.f, 0.f, 0.f}, {0.f, 0.f, 0.f, 0.f}};
#pragma unroll 4
  for (int kc = 0; kc < 16; ++kc) {
    bf16x8 af = *(const bf16x8*)(arow + kc * 32);
#pragma unroll
    for (int nt = 0; nt < 4; ++nt) {
      size_t woff = (size_t)(n0 + (nt << 4) + m16) * 512 + kc * 32 + (quad << 3);
      bf16x8 wh = *(const bf16x8*)(Whi + woff);
      bf16x8 wl = *(const bf16x8*)(Wlo + woff);
      acc[nt] = __builtin_amdgcn_mfma_f32_16x16x32_bf16(af, wh, acc[nt], 0, 0, 0);
      acc[nt] = __builtin_amdgcn_mfma_f32_16x16x32_bf16(af, wl, acc[nt], 0, 0, 0);
    }
  }
#pragma unroll
  for (int nt = 0; nt < 4; ++nt) {
    float bn = bias[n0 + (nt << 4) + m16];
#pragma unroll
    for (int r = 0; r < 4; ++r) {
      int i = i0 + (wave << 4) + (quad << 2) + r;
      out[(size_t)i * 512 + n0 + (nt << 4) + m16] = acc[nt][r] + bn;
    }
  }
}

// ============================================================================
extern "C" void kernel_launch(void* const* d_in, const int* in_sizes, int n_in,
                              void* d_out, int out_size, void* d_ws,
                              size_t ws_size, hipStream_t stream) {
  const float* query = (const float*)d_in[0];
  const float* key   = (const float*)d_in[1];
  const float* value = (const float*)d_in[2];
  const int*   mask  = (const int*)d_in[3];
  const float* Wq = (const float*)d_in[4];
  const float* bq = (const float*)d_in[5];
  const float* Wk = (const float*)d_in[6];
  const float* bk = (const float*)d_in[7];
  const float* Wv = (const float*)d_in[8];
  const float* bv = (const float*)d_in[9];
  const float* Wo = (const float*)d_in[10];
  const float* bo = (const float*)d_in[11];
  const float* rel = (const float*)d_in[12];

  char* w = (char*)d_ws;
  ushort* Qw    = (ushort*)w; w += (size_t)16 * 2048 * 64 * 2;        // 4 MiB
  ushort* Kw    = (ushort*)w; w += (size_t)16 * 2048 * 64 * 2;        // 4 MiB
  ushort* Vtw   = (ushort*)w; w += (size_t)16 * 64 * 2048 * 2;        // 4 MiB
  ushort* Whi   = (ushort*)w; w += (size_t)4 * 512 * 512 * 2;         // 2 MiB
  ushort* Wlo   = (ushort*)w; w += (size_t)4 * 512 * 512 * 2;         // 2 MiB
  ushort* qrelh = (ushort*)w; w += (size_t)16 * 2048 * NREL_PAD * 2;  // 31.3 MiB
  ushort* attnb = (ushort*)w; w += (size_t)4096 * 512 * 2;            // 4 MiB
  ushort* Opart = (ushort*)w; w += (size_t)4 * 16 * 2048 * 64 * 2;    // 16 MiB
  float*  mbuf  = (float*)w;  w += (size_t)4 * 16 * 2048 * 4;         // 0.5 MiB
  float*  lbuf  = (float*)w;  w += (size_t)4 * 16 * 2048 * 4;         // 0.5 MiB
  float* out = (float*)d_out;

  dim3 bb(256);
  hipLaunchKernelGGL(prep_wt, dim3(8, 8, 4), bb, 0, stream, Wq, Wk, Wv, Wo, Whi, Wlo);
  hipLaunchKernelGGL(proj_qkv, dim3(8, 64, 3), bb, 0, stream, query, key, value,
                     Whi, Wlo, bq, bk, bv, Qw, Kw, Vtw);
  hipLaunchKernelGGL(qrel_mfma, dim3(8, 32, 16), bb, 0, stream, Qw, rel, qrelh);
  hipLaunchKernelGGL(flash_attn, dim3(32, 16, 4), bb, 0, stream, Qw, Kw, Vtw,
                     qrelh, mask, Opart, mbuf, lbuf);
  hipLaunchKernelGGL(merge_attn, dim3(128), bb, 0, stream, Opart, mbuf, lbuf, attnb);
  hipLaunchKernelGGL(out_proj, dim3(8, 64), bb, 0, stream, attnb, Whi + 3 * 262144,
                     Wlo + 3 * 262144, bo, out);
}